// Round 20
// baseline (43.695 us; speedup 1.0000x reference)
//
#include <hip/hip_runtime.h>
#include <hip/hip_fp16.h>
#include <math.h>

// SSIM loss: r19 structure + 2-tile SOFTWARE PIPELINE on fragment reads.
// Slot s (tiles 0..5, buffers ping-pong buf[t&1]):
//   write_tile(t=s+1 -> buf[(s+1)&1])   [vmcnt waits prefetch regs]
//   load_tile(s+2)                      [issue next globals]
//   barrier (lgkmcnt(0)+s_barrier+sched_barrier(0))
//   issue ds_reads: frags(tile s+1)     [latency hides under compute]
//   compute(frags tile s, already in regs): 12 banded K=32 H-MFMAs
//     (Bh[j]=g[8am+j-cl-3]) -> D16 f16 once per (q,mt) -> register-chained
//     16x16x16 V-MFMAs (Av1[j]=g[4am+j-cl], Av2[j]=g[4am+j+16-cl]) -> SSIM.
// Hazard: reads of buf[q] (slot s) complete at own lgkmcnt(0) before
// barrier(s+1); next write of buf[q] is slot s+2, after ALL waves passed
// barrier(s+1). Unroll-by-2 with named FA/FB frag sets (no dyn indexing).
// LAUNCH BOUNDS MUST STAY (256,4): gfx950 unified VGPR/AGPR budget under
// (256,6)/(256,8) splits to 40/32 arch regs -> 100-300MB scratch, 3x slower
// (r15-r17). Grid 1024 = 4/CU assigned (r18: 8/CU regresses, FETCH +11MB).
// Zero-pad rows 42-47 / cols 80-103 zero-init'd both buffers, never written;
// V-weights for rows 42-47 provably zero; finite*0=0 invariant (r7-r19).

#define HH 512
#define WW 512
#define HW (HH*WW)
#define NPLANES 48
#define G_TILES 6
#define NBLOCKS 1024           // 6144 tiles / 6

typedef _Float16 f16x8 __attribute__((ext_vector_type(8)));
typedef _Float16 f16x4 __attribute__((ext_vector_type(4)));
typedef float f32x4 __attribute__((ext_vector_type(4)));

#define RAW_STRIDE 208         // bytes per staged row (104 f16; 80 used)
#define RAW_PLANE  9984        // 48*208; x at 0, y at RAW_PLANE
#define BUF_B      19968       // one buffer: 2 planes
#define LDS_TOTAL  39936       // 2 buffers (ping-pong)

struct WParam { float A, B; };

__global__ void ssim_init_out(float* out) { out[0] = 1.0f; }

__device__ __forceinline__ void barrier_nodrain() {
    asm volatile("s_waitcnt lgkmcnt(0)" ::: "memory");
    __builtin_amdgcn_s_barrier();
    __builtin_amdgcn_sched_barrier(0);
}

__global__ __launch_bounds__(256, 4)
void ssim_mfma(const float* __restrict__ img, const float* __restrict__ tgt,
               float* __restrict__ out, WParam wp) {
    __shared__ alignas(16) char lds[LDS_TOTAL];
    __shared__ float wsum[4];

    const int tid  = threadIdx.x;
    const int wid  = tid >> 6;
    const int lane = tid & 63;
    const int cl   = lane & 15;
    const int am   = lane >> 4;

    // fixed 2 staging items per thread (420 = 256 + 164)
    const int it0 = tid,       ir0 = it0 / 10, ig0 = it0 - 10 * ir0;
    const int it1 = tid + 256, ir1 = it1 / 10, ig1 = it1 - 10 * ir1;
    const bool has1 = (tid < 164);

    float4 Xa[2], Xb[2], Ya[2], Yb[2];

    auto load_tile = [&](int tlin) {
        const int p   = tlin >> 7;
        const int rem = tlin & 127;
        const int R0  = (rem >> 3) * 32;
        const int C0  = (rem & 7) * 64;
        const float* ip = img + (size_t)p * HW;
        const float* tp = tgt + (size_t)p * HW;
        #pragma unroll
        for (int s = 0; s < 2; ++s) {
            if (s == 1 && !has1) break;
            int r   = s ? ir1 : ir0;
            int grp = s ? ig1 : ig0;
            int gr  = R0 - 5 + r;
            int gc0 = C0 - 8 + grp * 8;
            float4 xa = make_float4(0.f,0.f,0.f,0.f), xb = xa, ya = xa, yb = xa;
            if ((unsigned)gr < (unsigned)HH) {
                const float* xr = ip + (size_t)gr * WW;
                const float* yr = tp + (size_t)gr * WW;
                if ((unsigned)gc0 <= (unsigned)(WW - 4)) {
                    xa = *(const float4*)(xr + gc0);
                    ya = *(const float4*)(yr + gc0);
                }
                if ((unsigned)(gc0 + 4) <= (unsigned)(WW - 4)) {
                    xb = *(const float4*)(xr + gc0 + 4);
                    yb = *(const float4*)(yr + gc0 + 4);
                }
            }
            Xa[s] = xa; Xb[s] = xb; Ya[s] = ya; Yb[s] = yb;
        }
    };

    auto write_tile = [&](char* buf) {
        #pragma unroll
        for (int s = 0; s < 2; ++s) {
            if (s == 1 && !has1) break;
            int r   = s ? ir1 : ir0;
            int grp = s ? ig1 : ig0;
            f16x8 hx, hy;
            hx[0]=(_Float16)Xa[s].x; hx[1]=(_Float16)Xa[s].y;
            hx[2]=(_Float16)Xa[s].z; hx[3]=(_Float16)Xa[s].w;
            hx[4]=(_Float16)Xb[s].x; hx[5]=(_Float16)Xb[s].y;
            hx[6]=(_Float16)Xb[s].z; hx[7]=(_Float16)Xb[s].w;
            hy[0]=(_Float16)Ya[s].x; hy[1]=(_Float16)Ya[s].y;
            hy[2]=(_Float16)Ya[s].z; hy[3]=(_Float16)Ya[s].w;
            hy[4]=(_Float16)Yb[s].x; hy[5]=(_Float16)Yb[s].y;
            hy[6]=(_Float16)Yb[s].z; hy[7]=(_Float16)Yb[s].w;
            char* base = buf + r * RAW_STRIDE + grp * 16;
            *(f16x8*)(base + 0*RAW_PLANE) = hx;
            *(f16x8*)(base + 1*RAW_PLANE) = hy;
        }
    };

    const int base_t = blockIdx.x * G_TILES;
    load_tile(base_t);                 // prefetch tile 0 (overlaps init)

    // ---- one-time LDS zero-init, BOTH buffers (pad regions stay zero) ----
    for (int i = tid; i < LDS_TOTAL / 4; i += 256)
        ((float*)lds)[i] = 0.f;

    // ---- per-lane weight fragments ----
    f16x8 Bh;
    #pragma unroll
    for (int j = 0; j < 8; ++j) {
        int ih = 8*am + j - cl - 3;
        float t = (float)(ih - 5);
        Bh[j] = ((unsigned)ih <= 10u) ? (_Float16)(wp.A * exp2f(-wp.B*t*t))
                                      : (_Float16)0.f;
    }
    f16x4 Av1, Av2;
    #pragma unroll
    for (int j = 0; j < 4; ++j) {
        int k = 4*am + j;
        int i1 = k - cl;
        float t1 = (float)(i1 - 5);
        Av1[j] = ((unsigned)i1 <= 10u) ? (_Float16)(wp.A * exp2f(-wp.B*t1*t1))
                                       : (_Float16)0.f;
        int i2 = k + 16 - cl;
        float t2 = (float)(i2 - 5);
        Av2[j] = ((unsigned)i2 <= 10u) ? (_Float16)(wp.A * exp2f(-wp.B*t2*t2))
                                       : (_Float16)0.f;
    }
    __syncthreads();

    const float C1 = 1e-4f, C2 = 9e-4f;
    float lsum = 0.f;
    const int abase = cl * RAW_STRIDE + 32 * wid + am * 16;

    // fragment sets (named, no dynamic indexing)
    f16x8 Ax0, Ax1, Ax2, Ay0, Ay1, Ay2;   // set A
    f16x8 Bx0, Bx1, Bx2, By0, By1, By2;   // set B

    auto read_frags_A = [&](const char* buf) {
        Ax0 = *(const f16x8*)(buf + abase);
        Ay0 = *(const f16x8*)(buf + RAW_PLANE + abase);
        Ax1 = *(const f16x8*)(buf + 16 * RAW_STRIDE + abase);
        Ay1 = *(const f16x8*)(buf + RAW_PLANE + 16 * RAW_STRIDE + abase);
        Ax2 = *(const f16x8*)(buf + 32 * RAW_STRIDE + abase);
        Ay2 = *(const f16x8*)(buf + RAW_PLANE + 32 * RAW_STRIDE + abase);
    };
    auto read_frags_B = [&](const char* buf) {
        Bx0 = *(const f16x8*)(buf + abase);
        By0 = *(const f16x8*)(buf + RAW_PLANE + abase);
        Bx1 = *(const f16x8*)(buf + 16 * RAW_STRIDE + abase);
        By1 = *(const f16x8*)(buf + RAW_PLANE + 16 * RAW_STRIDE + abase);
        Bx2 = *(const f16x8*)(buf + 32 * RAW_STRIDE + abase);
        By2 = *(const f16x8*)(buf + RAW_PLANE + 32 * RAW_STRIDE + abase);
    };

    auto compute = [&](f16x8 hx0, f16x8 hx1, f16x8 hx2,
                       f16x8 hy0, f16x8 hy1, f16x8 hy2) {
        f16x4 D16[4][3];
        #pragma unroll
        for (int q = 0; q < 4; ++q) {
            #pragma unroll
            for (int mt = 0; mt < 3; ++mt) {
                f16x8 hxm = (mt == 0) ? hx0 : (mt == 1) ? hx1 : hx2;
                f16x8 hym = (mt == 0) ? hy0 : (mt == 1) ? hy1 : hy2;
                f16x8 A = (q == 0) ? hxm
                        : (q == 1) ? hym
                        : (q == 2) ? (f16x8)(hxm*hxm + hym*hym)
                                   : (f16x8)(hxm*hym);
                f32x4 zz = {0.f, 0.f, 0.f, 0.f};
                f32x4 d = __builtin_amdgcn_mfma_f32_16x16x32_f16(A, Bh, zz, 0, 0, 0);
                f16x4 h;
                h[0]=(_Float16)d[0]; h[1]=(_Float16)d[1];
                h[2]=(_Float16)d[2]; h[3]=(_Float16)d[3];
                D16[q][mt] = h;
            }
        }
        #pragma unroll
        for (int mtv = 0; mtv < 2; ++mtv) {
            f32x4 accv[4];
            #pragma unroll
            for (int q = 0; q < 4; ++q) {
                f32x4 zz = {0.f, 0.f, 0.f, 0.f};
                f32x4 a = __builtin_amdgcn_mfma_f32_16x16x16f16(
                              Av2, D16[q][mtv+1], zz, 0, 0, 0);
                accv[q] = __builtin_amdgcn_mfma_f32_16x16x16f16(
                              Av1, D16[q][mtv], a, 0, 0, 0);
            }
            #pragma unroll
            for (int j = 0; j < 4; ++j) {
                float mu1 = accv[0][j], mu2 = accv[1][j];
                float bss = accv[2][j], bxy = accv[3][j];
                float mu1s = mu1*mu1, mu2s = mu2*mu2, mu12 = mu1*mu2;
                float ssum = bss - mu1s - mu2s;
                float s12  = bxy - mu12;
                float num = (2.f*mu12 + C1) * (2.f*s12 + C2);
                float den = (mu1s + mu2s + C1) * (ssum + C2);
                lsum = fmaf(num, __builtin_amdgcn_rcpf(den), lsum);
            }
        }
    };

    char* buf0 = lds;
    char* buf1 = lds + BUF_B;

    // ---- prologue: stage tile 0, read its frags into set A ----
    write_tile(buf0);
    load_tile(base_t + 1);
    barrier_nodrain();
    read_frags_A(buf0);

    // ---- pipelined slots, unrolled by 2 (G_TILES = 6) ----
    #pragma unroll 1
    for (int gp = 0; gp < G_TILES / 2 - 1; ++gp) {
        // even slot s=2gp: stage tile 2gp+1, read FB, compute FA (tile 2gp)
        write_tile(buf1);
        load_tile(base_t + 2*gp + 2);
        barrier_nodrain();
        read_frags_B(buf1);
        compute(Ax0, Ax1, Ax2, Ay0, Ay1, Ay2);
        // odd slot s=2gp+1: stage tile 2gp+2, read FA, compute FB
        write_tile(buf0);
        if (2*gp + 3 < G_TILES) load_tile(base_t + 2*gp + 3);
        barrier_nodrain();
        read_frags_A(buf0);
        compute(Bx0, Bx1, Bx2, By0, By1, By2);
    }
    // slot 4: stage tile 5, read FB, compute FA (tile 4)
    write_tile(buf1);
    barrier_nodrain();
    read_frags_B(buf1);
    compute(Ax0, Ax1, Ax2, Ay0, Ay1, Ay2);
    // slot 5: compute FB (tile 5)
    compute(Bx0, Bx1, Bx2, By0, By1, By2);

    // ---- block reduction + one atomic ----
    for (int off = 32; off > 0; off >>= 1)
        lsum += __shfl_down(lsum, off, 64);
    if (lane == 0) wsum[wid] = lsum;
    __syncthreads();
    if (tid == 0) {
        float bsum = wsum[0] + wsum[1] + wsum[2] + wsum[3];
        const float invN = 1.0f / (float)((size_t)NPLANES * HH * WW);
        atomicAdd(out, -bsum * invN);
    }
}

extern "C" void kernel_launch(void* const* d_in, const int* in_sizes, int n_in,
                              void* d_out, int out_size, void* d_ws, size_t ws_size,
                              hipStream_t stream) {
    const float* img = (const float*)d_in[0];
    const float* tgt = (const float*)d_in[1];
    float* out = (float*)d_out;

    // g[i] = exp(-(i-5)^2/4.5)/s = A * 2^(-B*(i-5)^2)
    double s = 0.0;
    for (int i = 0; i < 11; ++i) {
        double d = (double)(i - 5);
        s += exp(-(d * d) / 4.5);
    }
    WParam wp;
    wp.A = (float)(1.0 / s);
    wp.B = (float)(M_LOG2E / 4.5);

    ssim_init_out<<<1, 1, 0, stream>>>(out);
    ssim_mfma<<<NBLOCKS, 256, 0, stream>>>(img, tgt, out, wp);
}